// Round 5
// baseline (835.260 us; speedup 1.0000x reference)
//
#include <hip/hip_runtime.h>
#include <hip/hip_bf16.h>
#include <stdint.h>

// Problem constants (QRNN layer: SEQ=4096, BATCH=8, IN=1024, HID=1024)
#define S_   4096
#define B_   8
#define IN_  1024
#define H_   1024
#define M_   (S_ * B_)     // 32768 rows of the GEMM (row = s*B + b)
#define N_   (3 * H_)      // 3072 output cols (Z | F | O)
#define K_   IN_           // 1024
#define CH_  (B_ * H_)     // 8192 independent scan channels
#define NC_  256           // scan chunks (raised 64->256 for 4x scan TLP)
#define T_   (S_ / NC_)    // 16 steps per chunk
#define STRD (CH_ / 4)     // float4 stride between time steps

typedef unsigned short u16;
typedef __bf16 bf16x8 __attribute__((ext_vector_type(8)));
typedef float  f32x4  __attribute__((ext_vector_type(4)));

__device__ __forceinline__ u16 f2bf(float f) {
  unsigned u = __float_as_uint(f);
  u += 0x7fffu + ((u >> 16) & 1u);   // round-to-nearest-even
  return (u16)(u >> 16);
}

__device__ __forceinline__ float sigmoid_(float x) { return 1.0f / (1.0f + __expf(-x)); }
__device__ __forceinline__ float tanh_(float x)    { return 2.0f / (1.0f + __expf(-2.0f * x)) - 1.0f; }

// ---- fused fp32 -> bf16 conversion for X and W in ONE launch ----------------
__global__ void cvt_all(const float* __restrict__ X, const float* __restrict__ W,
                        u16* __restrict__ Xb, u16* __restrict__ Wb) {
  const int nX = M_ * K_ / 8, nW = N_ * K_ / 8;
  int i = blockIdx.x * blockDim.x + threadIdx.x;
  const float* in; u16* out; int j;
  if (i < nX)           { in = X; out = Xb; j = i; }
  else if (i < nX + nW) { in = W; out = Wb; j = i - nX; }
  else return;
  const float4* p = (const float4*)in;
  float4 a = p[2 * j], b = p[2 * j + 1];
  alignas(16) u16 us[8] = {f2bf(a.x), f2bf(a.y), f2bf(a.z), f2bf(a.w),
                           f2bf(b.x), f2bf(b.y), f2bf(b.z), f2bf(b.w)};
  ((uint4*)out)[j] = *(const uint4*)us;
}

// =============================================================================
// 256x256 8-phase bf16 MFMA GEMM (NT), fused activation epilogue.
// (UNCHANGED -- control.)
// =============================================================================
#define SWZ(x) ((x) ^ (((x) >> 3) & 0x30))

#define DS_A(s, h, mh) do {                                                    \
  const char* base_ = (const char*)As_[(s)*2+(h)];                             \
  af[0] = *(const bf16x8*)(base_ + aoff[mh][0]);                               \
  af[1] = *(const bf16x8*)(base_ + aoff[mh][1]);                               \
  af[2] = *(const bf16x8*)(base_ + aoff[mh][2]);                               \
  af[3] = *(const bf16x8*)(base_ + aoff[mh][3]);                               \
} while (0)

#define DS_B(s, h) do {                                                        \
  const char* base_ = (const char*)Bs_[(s)*2+(h)];                             \
  bfr[0] = *(const bf16x8*)(base_ + boff[0]);                                  \
  bfr[1] = *(const bf16x8*)(base_ + boff[1]);                                  \
  bfr[2] = *(const bf16x8*)(base_ + boff[2]);                                  \
  bfr[3] = *(const bf16x8*)(base_ + boff[3]);                                  \
} while (0)

#define MMA(mh) do {                                                           \
  __builtin_amdgcn_s_setprio(1);                                              \
  _Pragma("unroll")                                                            \
  for (int fi_ = 0; fi_ < 4; ++fi_)                                            \
    _Pragma("unroll")                                                          \
    for (int fj_ = 0; fj_ < 4; ++fj_)                                          \
      acc[(mh)*4+fi_][fj_] = __builtin_amdgcn_mfma_f32_16x16x32_bf16(          \
          af[fi_], bfr[fj_], acc[(mh)*4+fi_][fj_], 0, 0, 0);                   \
  __builtin_amdgcn_s_setprio(0);                                              \
} while (0)

#define PH_SYNC() do {                                                         \
  asm volatile("" ::: "memory");                                               \
  __builtin_amdgcn_s_barrier();                                                \
  asm volatile("s_waitcnt lgkmcnt(0)" ::: "memory");                           \
} while (0)

#define PH_END() do {                                                          \
  asm volatile("" ::: "memory");                                               \
  __builtin_amdgcn_s_barrier();                                                \
} while (0)

#define VW(n) asm volatile("s_waitcnt vmcnt(" #n ")" ::: "memory")

__global__ __launch_bounds__(512, 2) void gemm_act(
    const u16* __restrict__ Ab, const u16* __restrict__ Bb,
    const float* __restrict__ bias,
    float* __restrict__ zt,   // tanh(Z)  -> ws        [M_, H_]
    float* __restrict__ Cf,   // sigm(F)  -> C region  [M_, H_]
    float* __restrict__ Ho) { // sigm(O)  -> H region  [M_, H_]
  __shared__ alignas(16) u16 As_[4][8192];
  __shared__ alignas(16) u16 Bs_[4][8192];

  const int tid = threadIdx.x;
  const int w = tid >> 6, l = tid & 63;
  const int m0 = blockIdx.y * 256, n0 = blockIdx.x * 256;
  const int wmo = (w >> 2) * 128, wno = (w & 3) * 64;
  const int lr = l & 15, lq = l >> 4;

  const int D0b  = w * 1024 + l * 16;
  const int row0 = D0b >> 6;
  const int c0   = (SWZ(D0b) & 63) >> 1;

  int aoff[2][4], boff[4];
#pragma unroll
  for (int mh = 0; mh < 2; ++mh)
#pragma unroll
    for (int fi = 0; fi < 4; ++fi)
      aoff[mh][fi] = SWZ((wmo + (mh * 4 + fi) * 16 + lr) * 64 + lq * 16);
#pragma unroll
  for (int fj = 0; fj < 4; ++fj)
    boff[fj] = SWZ((wno + fj * 16 + lr) * 64 + lq * 16);

  auto stage = [&](const u16* __restrict__ G, int rb, int tt, int hh, u16* dstp) {
    const u16* s0 = G + (size_t)(rb + row0) * K_ + (tt * 64 + hh * 32 + c0);
    __builtin_amdgcn_global_load_lds(
        (const __attribute__((address_space(1))) void*)s0,
        (__attribute__((address_space(3))) void*)(dstp + (D0b >> 1)), 16, 0, 0);
    const u16* s1 = s0 + (size_t)128 * K_;
    __builtin_amdgcn_global_load_lds(
        (const __attribute__((address_space(1))) void*)s1,
        (__attribute__((address_space(3))) void*)(dstp + (D0b >> 1) + 4096), 16, 0, 0);
  };

  f32x4 acc[8][4] = {};
  bf16x8 af[4], bfr[4];

  stage(Ab, m0, 0, 0, As_[0]); stage(Bb, n0, 0, 0, Bs_[0]);
  stage(Ab, m0, 0, 1, As_[1]); stage(Bb, n0, 0, 1, Bs_[1]);
  stage(Ab, m0, 1, 0, As_[2]); stage(Bb, n0, 1, 0, Bs_[2]);
  VW(4);
  PH_END();

  for (int i = 0; i < 7; ++i) {
    const int t1 = 2 * i + 1, t2 = 2 * i + 2, t3 = 2 * i + 3;
    DS_A(0, 0, 0); DS_B(0, 0); stage(Ab, m0, t1, 1, As_[3]);
    PH_SYNC(); MMA(0); PH_END();
    DS_A(0, 0, 1);             stage(Bb, n0, t1, 1, Bs_[3]);
    PH_SYNC(); MMA(1); PH_END();
    DS_A(0, 1, 0); DS_B(0, 1); stage(Ab, m0, t2, 0, As_[0]);
    PH_SYNC(); MMA(0); PH_END();
    DS_A(0, 1, 1);             stage(Bb, n0, t2, 0, Bs_[0]); VW(4);
    PH_SYNC(); MMA(1); PH_END();
    DS_A(1, 0, 0); DS_B(1, 0); stage(Ab, m0, t2, 1, As_[1]);
    PH_SYNC(); MMA(0); PH_END();
    DS_A(1, 0, 1);             stage(Bb, n0, t2, 1, Bs_[1]);
    PH_SYNC(); MMA(1); PH_END();
    DS_A(1, 1, 0); DS_B(1, 1); stage(Ab, m0, t3, 0, As_[2]);
    PH_SYNC(); MMA(0); PH_END();
    DS_A(1, 1, 1);             stage(Bb, n0, t3, 0, Bs_[2]); VW(4);
    PH_SYNC(); MMA(1); PH_END();
  }

  DS_A(0, 0, 0); DS_B(0, 0); stage(Ab, m0, 15, 1, As_[3]);
  PH_SYNC(); MMA(0); PH_END();
  DS_A(0, 0, 1);             stage(Bb, n0, 15, 1, Bs_[3]);
  PH_SYNC(); MMA(1); PH_END();
  DS_A(0, 1, 0); DS_B(0, 1);
  PH_SYNC(); MMA(0); PH_END();
  DS_A(0, 1, 1); VW(0);
  PH_SYNC(); MMA(1); PH_END();
  DS_A(1, 0, 0); DS_B(1, 0);
  PH_SYNC(); MMA(0); PH_END();
  DS_A(1, 0, 1);
  PH_SYNC(); MMA(1); PH_END();
  DS_A(1, 1, 0); DS_B(1, 1);
  PH_SYNC(); MMA(0); PH_END();
  DS_A(1, 1, 1);
  PH_SYNC(); MMA(1); PH_END();

  const int seg = n0 >> 10;
  const int nh0 = (n0 & 1023) + wno;
  float* dst = (seg == 0) ? zt : (seg == 1 ? Cf : Ho);
#pragma unroll
  for (int fj = 0; fj < 4; ++fj) {
    const int nn = nh0 + fj * 16 + lr;
    const float bv = bias[seg * 1024 + nn];
#pragma unroll
    for (int fi = 0; fi < 8; ++fi) {
#pragma unroll
      for (int rr = 0; rr < 4; ++rr) {
        const int mm = m0 + wmo + fi * 16 + lq * 4 + rr;
        const float v = acc[fi][fj][rr] + bv;
        dst[(size_t)mm * H_ + nn] = (seg == 0) ? tanh_(v) : sigmoid_(v);
      }
    }
  }
}

// =============================================================================
// Scan kernels, NC=256: 2048 blocks -> 8 blocks/CU -> 32 waves/CU (full TLP),
// float4 channels + depth-2 rolling prefetch. Per-channel op order identical.
// =============================================================================

#define UPDA4(ff, zz) do { float om_;                                          \
  om_ = 1.f - (ff).x; c.x = (ff).x * (zz).x + om_ * c.x; A.x *= om_;           \
  om_ = 1.f - (ff).y; c.y = (ff).y * (zz).y + om_ * c.y; A.y *= om_;           \
  om_ = 1.f - (ff).z; c.z = (ff).z * (zz).z + om_ * c.z; A.z *= om_;           \
  om_ = 1.f - (ff).w; c.w = (ff).w * (zz).w + om_ * c.w; A.w *= om_;           \
} while (0)

#define UPDB4(ff, zz) do {                                                     \
  c.x = (ff).x * (zz).x + (1.f - (ff).x) * c.x;                                \
  c.y = (ff).y * (zz).y + (1.f - (ff).y) * c.y;                                \
  c.z = (ff).z * (zz).z + (1.f - (ff).z) * c.z;                                \
  c.w = (ff).w * (zz).w + (1.f - (ff).w) * c.w;                                \
} while (0)

// ---- scan pass A: per-chunk (prod(1-f), local c_end with c_in = 0) ----------
__global__ void scanA(const float* __restrict__ Cf, const float* __restrict__ zt,
                      float* __restrict__ ckA, float* __restrict__ ckC) {
  const int ch4 = blockIdx.x * 256 + threadIdx.x;   // float4 channel idx (0..2047)
  const int j   = blockIdx.y;                        // chunk (0..255)
  const float4* __restrict__ Cf4 = (const float4*)Cf;
  const float4* __restrict__ zt4 = (const float4*)zt;
  size_t base = (size_t)j * T_ * STRD + ch4;
  float4 A = {1.f, 1.f, 1.f, 1.f}, c = {0.f, 0.f, 0.f, 0.f};
  float4 f0 = Cf4[base],        z0 = zt4[base];
  float4 f1 = Cf4[base + STRD], z1 = zt4[base + STRD];
#pragma unroll
  for (int tt = 0; tt < T_ - 2; ++tt) {
    const float4 fn = Cf4[base + 2 * STRD];   // keep 2 steps in flight
    const float4 zn = zt4[base + 2 * STRD];
    UPDA4(f0, z0);
    f0 = f1; z0 = z1; f1 = fn; z1 = zn;
    base += STRD;
  }
  UPDA4(f0, z0);
  UPDA4(f1, z1);
  ((float4*)ckA)[(size_t)j * STRD + ch4] = A;
  ((float4*)ckC)[(size_t)j * STRD + ch4] = c;
}

// ---- scan combine: sequential over NC_ chunks, seeded with hidden -----------
// Chain is one FMA per chunk; loads are chain-independent -> prefetch + unroll.
__global__ void scanComb(const float* __restrict__ ckA, const float* __restrict__ ckC,
                         const float* __restrict__ hidden, float* __restrict__ carry) {
  const int ch4 = blockIdx.x * 64 + threadIdx.x;    // 32 blocks x 64 threads
  const float4* __restrict__ a4 = (const float4*)ckA;
  const float4* __restrict__ c4 = (const float4*)ckC;
  float4* __restrict__ cr4 = (float4*)carry;
  float4 c = ((const float4*)hidden)[ch4];
  float4 A0 = a4[ch4], C0 = c4[ch4];
#pragma unroll 8
  for (int j = 0; j < NC_ - 1; ++j) {
    const float4 A1 = a4[(size_t)(j + 1) * STRD + ch4];   // prefetch next
    const float4 C1 = c4[(size_t)(j + 1) * STRD + ch4];
    cr4[(size_t)j * STRD + ch4] = c;                      // c entering chunk j
    c.x = C0.x + A0.x * c.x;
    c.y = C0.y + A0.y * c.y;
    c.z = C0.z + A0.z * c.z;
    c.w = C0.w + A0.w * c.w;
    A0 = A1; C0 = C1;
  }
  cr4[(size_t)(NC_ - 1) * STRD + ch4] = c;
}

// ---- scan pass B: replay with true carry; write C and H in place ------------
__global__ void scanB(float* __restrict__ Cf,          // in: sigm(F), out: C
                      const float* __restrict__ zt,    // tanh(Z)
                      float* __restrict__ Ho,          // in: sigm(O), out: H
                      float* __restrict__ Clast,       // [CH_]
                      const float* __restrict__ carry) {
  const int ch4 = blockIdx.x * 256 + threadIdx.x;
  const int j   = blockIdx.y;
  float4* __restrict__ Cf4 = (float4*)Cf;
  const float4* __restrict__ zt4 = (const float4*)zt;
  float4* __restrict__ Ho4 = (float4*)Ho;
  size_t base = (size_t)j * T_ * STRD + ch4;
  float4 c = ((const float4*)carry)[(size_t)j * STRD + ch4];
  float4 f0 = Cf4[base],        z0 = zt4[base],        o0 = Ho4[base];
  float4 f1 = Cf4[base + STRD], z1 = zt4[base + STRD], o1 = Ho4[base + STRD];
#pragma unroll
  for (int tt = 0; tt < T_ - 2; ++tt) {
    const float4 fn = Cf4[base + 2 * STRD];   // keep 2 steps in flight
    const float4 zn = zt4[base + 2 * STRD];
    const float4 on = Ho4[base + 2 * STRD];
    UPDB4(f0, z0);
    Cf4[base] = c;
    Ho4[base] = float4{o0.x * c.x, o0.y * c.y, o0.z * c.z, o0.w * c.w};
    f0 = f1; z0 = z1; o0 = o1; f1 = fn; z1 = zn; o1 = on;
    base += STRD;
  }
  UPDB4(f0, z0);
  Cf4[base] = c;
  Ho4[base] = float4{o0.x * c.x, o0.y * c.y, o0.z * c.z, o0.w * c.w};
  base += STRD;
  UPDB4(f1, z1);
  Cf4[base] = c;
  Ho4[base] = float4{o1.x * c.x, o1.y * c.y, o1.z * c.z, o1.w * c.w};
  if (j == NC_ - 1) ((float4*)Clast)[ch4] = c;
}

extern "C" void kernel_launch(void* const* d_in, const int* in_sizes, int n_in,
                              void* d_out, int out_size, void* d_ws, size_t ws_size,
                              hipStream_t stream) {
  const float* X    = (const float*)d_in[0];   // [S,B,IN]
  const float* hid  = (const float*)d_in[1];   // [B,H]
  const float* W    = (const float*)d_in[2];   // [3H,IN]
  const float* bias = (const float*)d_in[3];   // [3H]

  float* out   = (float*)d_out;
  float* Ho    = out;                          // H       [S,B,H]
  float* Clast = out + (size_t)M_ * H_;        // C[-1:]  [1,B,H]
  float* Cf    = Clast + CH_;                  // C       [S,B,H]

  char* ws = (char*)d_ws;
  u16*  Xb    = (u16*)ws;                      //  67108864 B bf16 X
  u16*  Wb    = (u16*)(ws + 67108864);         //   6291456 B bf16 W
  float* zt   = (float*)(ws + 73400320);       // 134217728 B tanh(Z)
  // ckA/ckC/carry (8 MB each, NC_=256) overlay Xb's region: Xb is dead after
  // gemm_act; scanA writes them strictly later in stream order. ws use: 198 MiB.
  float* ckA  = (float*)(ws);
  float* ckC  = (float*)(ws + 8388608);
  float* carry= (float*)(ws + 16777216);

  const int nAll = M_ * K_ / 8 + N_ * K_ / 8;
  cvt_all<<<(nAll + 255) / 256, 256, 0, stream>>>(X, W, Xb, Wb);
  gemm_act<<<dim3(N_ / 256, M_ / 256), 512, 0, stream>>>(Xb, Wb, bias, zt, Cf, Ho);
  scanA<<<dim3(CH_ / 1024, NC_), 256, 0, stream>>>(Cf, zt, ckA, ckC);
  scanComb<<<CH_ / 4 / 64, 64, 0, stream>>>(ckA, ckC, hid, carry);
  scanB<<<dim3(CH_ / 1024, NC_), 256, 0, stream>>>(Cf, zt, Ho, Clast, carry);
}

// Round 6
// 770.399 us; speedup vs baseline: 1.0842x; 1.0842x over previous
//
#include <hip/hip_runtime.h>
#include <hip/hip_bf16.h>
#include <stdint.h>

// Problem constants (QRNN layer: SEQ=4096, BATCH=8, IN=1024, HID=1024)
#define S_   4096
#define B_   8
#define IN_  1024
#define H_   1024
#define M_   (S_ * B_)     // 32768 rows of the GEMM (row = s*B + b)
#define N_   (3 * H_)      // 3072 output cols (Z | F | O)
#define K_   IN_           // 1024
#define CH_  (B_ * H_)     // 8192 independent scan channels
#define NC_  64            // scan chunks (reverted 256->64: R5 regression)
#define T_   (S_ / NC_)    // 64 steps per chunk
#define STR8 (CH_ / 8)     // half8 stride between time steps
#define STR4 (CH_ / 4)     // float4 stride between time steps

typedef unsigned short u16;
typedef __bf16 bf16x8 __attribute__((ext_vector_type(8)));
typedef float  f32x4  __attribute__((ext_vector_type(4)));
typedef _Float16 h8   __attribute__((ext_vector_type(8)));

__device__ __forceinline__ u16 f2bf(float f) {
  unsigned u = __float_as_uint(f);
  u += 0x7fffu + ((u >> 16) & 1u);   // round-to-nearest-even
  return (u16)(u >> 16);
}

__device__ __forceinline__ float sigmoid_(float x) { return 1.0f / (1.0f + __expf(-x)); }
__device__ __forceinline__ float tanh_(float x)    { return 2.0f / (1.0f + __expf(-2.0f * x)) - 1.0f; }

// ---- fused fp32 -> bf16 conversion for X and W in ONE launch ----------------
__global__ void cvt_all(const float* __restrict__ X, const float* __restrict__ W,
                        u16* __restrict__ Xb, u16* __restrict__ Wb) {
  const int nX = M_ * K_ / 8, nW = N_ * K_ / 8;
  int i = blockIdx.x * blockDim.x + threadIdx.x;
  const float* in; u16* out; int j;
  if (i < nX)           { in = X; out = Xb; j = i; }
  else if (i < nX + nW) { in = W; out = Wb; j = i - nX; }
  else return;
  const float4* p = (const float4*)in;
  float4 a = p[2 * j], b = p[2 * j + 1];
  alignas(16) u16 us[8] = {f2bf(a.x), f2bf(a.y), f2bf(a.z), f2bf(a.w),
                           f2bf(b.x), f2bf(b.y), f2bf(b.z), f2bf(b.w)};
  ((uint4*)out)[j] = *(const uint4*)us;
}

// =============================================================================
// 256x256 8-phase bf16 MFMA GEMM (NT), fused activation epilogue.
// Mainloop UNCHANGED (control). Epilogue: z=tanh(Z), f=sigm(F) now stored as
// fp16 in ws (halves gate-read traffic downstream); o=sigm(O) stays fp32 in
// d_out's H region for scanB's in-place RMW.
// =============================================================================
#define SWZ(x) ((x) ^ (((x) >> 3) & 0x30))

#define DS_A(s, h, mh) do {                                                    \
  const char* base_ = (const char*)As_[(s)*2+(h)];                             \
  af[0] = *(const bf16x8*)(base_ + aoff[mh][0]);                               \
  af[1] = *(const bf16x8*)(base_ + aoff[mh][1]);                               \
  af[2] = *(const bf16x8*)(base_ + aoff[mh][2]);                               \
  af[3] = *(const bf16x8*)(base_ + aoff[mh][3]);                               \
} while (0)

#define DS_B(s, h) do {                                                        \
  const char* base_ = (const char*)Bs_[(s)*2+(h)];                             \
  bfr[0] = *(const bf16x8*)(base_ + boff[0]);                                  \
  bfr[1] = *(const bf16x8*)(base_ + boff[1]);                                  \
  bfr[2] = *(const bf16x8*)(base_ + boff[2]);                                  \
  bfr[3] = *(const bf16x8*)(base_ + boff[3]);                                  \
} while (0)

#define MMA(mh) do {                                                           \
  __builtin_amdgcn_s_setprio(1);                                              \
  _Pragma("unroll")                                                            \
  for (int fi_ = 0; fi_ < 4; ++fi_)                                            \
    _Pragma("unroll")                                                          \
    for (int fj_ = 0; fj_ < 4; ++fj_)                                          \
      acc[(mh)*4+fi_][fj_] = __builtin_amdgcn_mfma_f32_16x16x32_bf16(          \
          af[fi_], bfr[fj_], acc[(mh)*4+fi_][fj_], 0, 0, 0);                   \
  __builtin_amdgcn_s_setprio(0);                                              \
} while (0)

#define PH_SYNC() do {                                                         \
  asm volatile("" ::: "memory");                                               \
  __builtin_amdgcn_s_barrier();                                                \
  asm volatile("s_waitcnt lgkmcnt(0)" ::: "memory");                           \
} while (0)

#define PH_END() do {                                                          \
  asm volatile("" ::: "memory");                                               \
  __builtin_amdgcn_s_barrier();                                                \
} while (0)

#define VW(n) asm volatile("s_waitcnt vmcnt(" #n ")" ::: "memory")

__global__ __launch_bounds__(512, 2) void gemm_act(
    const u16* __restrict__ Ab, const u16* __restrict__ Bb,
    const float* __restrict__ bias,
    _Float16* __restrict__ zh,  // tanh(Z)  fp16 -> ws   [M_, H_]
    _Float16* __restrict__ fh,  // sigm(F)  fp16 -> ws   [M_, H_]
    float* __restrict__ Ho) {   // sigm(O)  fp32 -> H region of d_out
  __shared__ alignas(16) u16 As_[4][8192];
  __shared__ alignas(16) u16 Bs_[4][8192];

  const int tid = threadIdx.x;
  const int w = tid >> 6, l = tid & 63;
  const int m0 = blockIdx.y * 256, n0 = blockIdx.x * 256;
  const int wmo = (w >> 2) * 128, wno = (w & 3) * 64;
  const int lr = l & 15, lq = l >> 4;

  const int D0b  = w * 1024 + l * 16;
  const int row0 = D0b >> 6;
  const int c0   = (SWZ(D0b) & 63) >> 1;

  int aoff[2][4], boff[4];
#pragma unroll
  for (int mh = 0; mh < 2; ++mh)
#pragma unroll
    for (int fi = 0; fi < 4; ++fi)
      aoff[mh][fi] = SWZ((wmo + (mh * 4 + fi) * 16 + lr) * 64 + lq * 16);
#pragma unroll
  for (int fj = 0; fj < 4; ++fj)
    boff[fj] = SWZ((wno + fj * 16 + lr) * 64 + lq * 16);

  auto stage = [&](const u16* __restrict__ G, int rb, int tt, int hh, u16* dstp) {
    const u16* s0 = G + (size_t)(rb + row0) * K_ + (tt * 64 + hh * 32 + c0);
    __builtin_amdgcn_global_load_lds(
        (const __attribute__((address_space(1))) void*)s0,
        (__attribute__((address_space(3))) void*)(dstp + (D0b >> 1)), 16, 0, 0);
    const u16* s1 = s0 + (size_t)128 * K_;
    __builtin_amdgcn_global_load_lds(
        (const __attribute__((address_space(1))) void*)s1,
        (__attribute__((address_space(3))) void*)(dstp + (D0b >> 1) + 4096), 16, 0, 0);
  };

  f32x4 acc[8][4] = {};
  bf16x8 af[4], bfr[4];

  stage(Ab, m0, 0, 0, As_[0]); stage(Bb, n0, 0, 0, Bs_[0]);
  stage(Ab, m0, 0, 1, As_[1]); stage(Bb, n0, 0, 1, Bs_[1]);
  stage(Ab, m0, 1, 0, As_[2]); stage(Bb, n0, 1, 0, Bs_[2]);
  VW(4);
  PH_END();

  for (int i = 0; i < 7; ++i) {
    const int t1 = 2 * i + 1, t2 = 2 * i + 2, t3 = 2 * i + 3;
    DS_A(0, 0, 0); DS_B(0, 0); stage(Ab, m0, t1, 1, As_[3]);
    PH_SYNC(); MMA(0); PH_END();
    DS_A(0, 0, 1);             stage(Bb, n0, t1, 1, Bs_[3]);
    PH_SYNC(); MMA(1); PH_END();
    DS_A(0, 1, 0); DS_B(0, 1); stage(Ab, m0, t2, 0, As_[0]);
    PH_SYNC(); MMA(0); PH_END();
    DS_A(0, 1, 1);             stage(Bb, n0, t2, 0, Bs_[0]); VW(4);
    PH_SYNC(); MMA(1); PH_END();
    DS_A(1, 0, 0); DS_B(1, 0); stage(Ab, m0, t2, 1, As_[1]);
    PH_SYNC(); MMA(0); PH_END();
    DS_A(1, 0, 1);             stage(Bb, n0, t2, 1, Bs_[1]);
    PH_SYNC(); MMA(1); PH_END();
    DS_A(1, 1, 0); DS_B(1, 1); stage(Ab, m0, t3, 0, As_[2]);
    PH_SYNC(); MMA(0); PH_END();
    DS_A(1, 1, 1);             stage(Bb, n0, t3, 0, Bs_[2]); VW(4);
    PH_SYNC(); MMA(1); PH_END();
  }

  DS_A(0, 0, 0); DS_B(0, 0); stage(Ab, m0, 15, 1, As_[3]);
  PH_SYNC(); MMA(0); PH_END();
  DS_A(0, 0, 1);             stage(Bb, n0, 15, 1, Bs_[3]);
  PH_SYNC(); MMA(1); PH_END();
  DS_A(0, 1, 0); DS_B(0, 1);
  PH_SYNC(); MMA(0); PH_END();
  DS_A(0, 1, 1); VW(0);
  PH_SYNC(); MMA(1); PH_END();
  DS_A(1, 0, 0); DS_B(1, 0);
  PH_SYNC(); MMA(0); PH_END();
  DS_A(1, 0, 1);
  PH_SYNC(); MMA(1); PH_END();
  DS_A(1, 1, 0); DS_B(1, 1);
  PH_SYNC(); MMA(0); PH_END();
  DS_A(1, 1, 1);
  PH_SYNC(); MMA(1); PH_END();

  // Epilogue: tile is 256 cols, segment-aligned. seg 0 -> z_h (fp16),
  // seg 1 -> f_h (fp16), seg 2 -> Ho (fp32).
  const int seg = n0 >> 10;
  const int nh0 = (n0 & 1023) + wno;
#pragma unroll
  for (int fj = 0; fj < 4; ++fj) {
    const int nn = nh0 + fj * 16 + lr;
    const float bv = bias[seg * 1024 + nn];
#pragma unroll
    for (int fi = 0; fi < 8; ++fi) {
#pragma unroll
      for (int rr = 0; rr < 4; ++rr) {
        const int mm = m0 + wmo + fi * 16 + lq * 4 + rr;
        const float v = acc[fi][fj][rr] + bv;
        const size_t idx = (size_t)mm * H_ + nn;
        if (seg == 0)      zh[idx] = (_Float16)tanh_(v);
        else if (seg == 1) fh[idx] = (_Float16)sigmoid_(v);
        else               Ho[idx] = sigmoid_(v);
      }
    }
  }
}

// =============================================================================
// Scan kernels: fp16 gates (8 ch/thread = 16 B loads), fp32 state/outputs,
// depth-2 rolling prefetch. Per-channel op order identical to reference.
// =============================================================================

// ---- scan pass A: per-chunk (prod(1-f), local c_end with c_in = 0) ----------
__global__ void scanA(const _Float16* __restrict__ fhp, const _Float16* __restrict__ zhp,
                      float* __restrict__ ckA, float* __restrict__ ckC) {
  const int ch8 = blockIdx.x * 256 + threadIdx.x;   // half8 channel idx (0..1023)
  const int j   = blockIdx.y;                        // chunk (0..63)
  const h8* __restrict__ fh = (const h8*)fhp;
  const h8* __restrict__ zh = (const h8*)zhp;
  size_t base = (size_t)j * T_ * STR8 + ch8;
  float A[8], c[8];
#pragma unroll
  for (int k = 0; k < 8; ++k) { A[k] = 1.f; c[k] = 0.f; }
  h8 f0 = fh[base],        z0 = zh[base];
  h8 f1 = fh[base + STR8], z1 = zh[base + STR8];
  for (int tt = 0; tt < T_ - 2; ++tt) {
    const h8 f2 = fh[base + 2 * STR8];   // keep 2 steps in flight
    const h8 z2 = zh[base + 2 * STR8];
#pragma unroll
    for (int k = 0; k < 8; ++k) {
      const float f = (float)f0[k], z = (float)z0[k], om = 1.f - f;
      c[k] = f * z + om * c[k]; A[k] *= om;
    }
    f0 = f1; z0 = z1; f1 = f2; z1 = z2; base += STR8;
  }
#pragma unroll
  for (int k = 0; k < 8; ++k) {
    const float f = (float)f0[k], z = (float)z0[k], om = 1.f - f;
    c[k] = f * z + om * c[k]; A[k] *= om;
  }
#pragma unroll
  for (int k = 0; k < 8; ++k) {
    const float f = (float)f1[k], z = (float)z1[k], om = 1.f - f;
    c[k] = f * z + om * c[k]; A[k] *= om;
  }
  float4* a4 = (float4*)ckA; float4* c4 = (float4*)ckC;
  const size_t o4 = (size_t)j * STR4 + ch8 * 2;
  a4[o4]     = float4{A[0], A[1], A[2], A[3]};
  a4[o4 + 1] = float4{A[4], A[5], A[6], A[7]};
  c4[o4]     = float4{c[0], c[1], c[2], c[3]};
  c4[o4 + 1] = float4{c[4], c[5], c[6], c[7]};
}

// ---- scan combine: sequential over NC_ chunks, seeded with hidden -----------
__global__ void scanComb(const float* __restrict__ ckA, const float* __restrict__ ckC,
                         const float* __restrict__ hidden, float* __restrict__ carry) {
  const int ch4 = blockIdx.x * 64 + threadIdx.x;    // 32 blocks x 64 threads
  const float4* __restrict__ a4 = (const float4*)ckA;
  const float4* __restrict__ c4 = (const float4*)ckC;
  float4* __restrict__ cr4 = (float4*)carry;
  float4 c = ((const float4*)hidden)[ch4];
  float4 A0 = a4[ch4], C0 = c4[ch4];
#pragma unroll 8
  for (int j = 0; j < NC_ - 1; ++j) {
    const float4 A1 = a4[(size_t)(j + 1) * STR4 + ch4];   // prefetch next
    const float4 C1 = c4[(size_t)(j + 1) * STR4 + ch4];
    cr4[(size_t)j * STR4 + ch4] = c;                      // c entering chunk j
    c.x = C0.x + A0.x * c.x;
    c.y = C0.y + A0.y * c.y;
    c.z = C0.z + A0.z * c.z;
    c.w = C0.w + A0.w * c.w;
    A0 = A1; C0 = C1;
  }
  cr4[(size_t)(NC_ - 1) * STR4 + ch4] = c;
}

// ---- scan pass B: replay with true carry; write C fresh, H in place ---------
__global__ void scanB(const _Float16* __restrict__ fhp, const _Float16* __restrict__ zhp,
                      float* __restrict__ Cw,           // C out fp32 [S,B,H]
                      float* __restrict__ Ho,           // in: sigm(O), out: H
                      float* __restrict__ Clast,        // [CH_]
                      const float* __restrict__ carry) {
  const int ch8 = blockIdx.x * 256 + threadIdx.x;
  const int j   = blockIdx.y;
  const h8* __restrict__ fh = (const h8*)fhp;
  const h8* __restrict__ zh = (const h8*)zhp;
  float4* __restrict__ H4 = (float4*)Ho;
  float4* __restrict__ C4 = (float4*)Cw;
  size_t b8 = (size_t)j * T_ * STR8 + ch8;
  size_t b4 = (size_t)j * T_ * STR4 + ch8 * 2;
  const float4 ca = ((const float4*)carry)[(size_t)j * STR4 + ch8 * 2];
  const float4 cb = ((const float4*)carry)[(size_t)j * STR4 + ch8 * 2 + 1];
  float c[8] = {ca.x, ca.y, ca.z, ca.w, cb.x, cb.y, cb.z, cb.w};
  h8 f0 = fh[b8],        z0 = zh[b8];
  float4 oa0 = H4[b4], ob0 = H4[b4 + 1];
  h8 f1 = fh[b8 + STR8], z1 = zh[b8 + STR8];
  float4 oa1 = H4[b4 + STR4], ob1 = H4[b4 + STR4 + 1];
  for (int tt = 0; tt < T_ - 2; ++tt) {
    const h8 f2 = fh[b8 + 2 * STR8];     // keep 2 steps in flight
    const h8 z2 = zh[b8 + 2 * STR8];
    const float4 oa2 = H4[b4 + 2 * STR4], ob2 = H4[b4 + 2 * STR4 + 1];
#pragma unroll
    for (int k = 0; k < 8; ++k) {
      const float f = (float)f0[k], z = (float)z0[k];
      c[k] = f * z + (1.f - f) * c[k];
    }
    C4[b4]     = float4{c[0], c[1], c[2], c[3]};
    C4[b4 + 1] = float4{c[4], c[5], c[6], c[7]};
    H4[b4]     = float4{oa0.x * c[0], oa0.y * c[1], oa0.z * c[2], oa0.w * c[3]};
    H4[b4 + 1] = float4{ob0.x * c[4], ob0.y * c[5], ob0.z * c[6], ob0.w * c[7]};
    f0 = f1; z0 = z1; oa0 = oa1; ob0 = ob1;
    f1 = f2; z1 = z2; oa1 = oa2; ob1 = ob2;
    b8 += STR8; b4 += STR4;
  }
#pragma unroll
  for (int k = 0; k < 8; ++k) {
    const float f = (float)f0[k], z = (float)z0[k];
    c[k] = f * z + (1.f - f) * c[k];
  }
  C4[b4]     = float4{c[0], c[1], c[2], c[3]};
  C4[b4 + 1] = float4{c[4], c[5], c[6], c[7]};
  H4[b4]     = float4{oa0.x * c[0], oa0.y * c[1], oa0.z * c[2], oa0.w * c[3]};
  H4[b4 + 1] = float4{ob0.x * c[4], ob0.y * c[5], ob0.z * c[6], ob0.w * c[7]};
  b4 += STR4;
#pragma unroll
  for (int k = 0; k < 8; ++k) {
    const float f = (float)f1[k], z = (float)z1[k];
    c[k] = f * z + (1.f - f) * c[k];
  }
  C4[b4]     = float4{c[0], c[1], c[2], c[3]};
  C4[b4 + 1] = float4{c[4], c[5], c[6], c[7]};
  H4[b4]     = float4{oa1.x * c[0], oa1.y * c[1], oa1.z * c[2], oa1.w * c[3]};
  H4[b4 + 1] = float4{ob1.x * c[4], ob1.y * c[5], ob1.z * c[6], ob1.w * c[7]};
  if (j == NC_ - 1) {
    ((float4*)Clast)[ch8 * 2]     = float4{c[0], c[1], c[2], c[3]};
    ((float4*)Clast)[ch8 * 2 + 1] = float4{c[4], c[5], c[6], c[7]};
  }
}

extern "C" void kernel_launch(void* const* d_in, const int* in_sizes, int n_in,
                              void* d_out, int out_size, void* d_ws, size_t ws_size,
                              hipStream_t stream) {
  const float* X    = (const float*)d_in[0];   // [S,B,IN]
  const float* hid  = (const float*)d_in[1];   // [B,H]
  const float* W    = (const float*)d_in[2];   // [3H,IN]
  const float* bias = (const float*)d_in[3];   // [3H]

  float* out   = (float*)d_out;
  float* Ho    = out;                          // H       [S,B,H]
  float* Clast = out + (size_t)M_ * H_;        // C[-1:]  [1,B,H]
  float* Cf    = Clast + CH_;                  // C       [S,B,H]

  char* ws = (char*)d_ws;
  u16*      Xb  = (u16*)ws;                    //  67108864 B bf16 X
  u16*      Wb  = (u16*)(ws + 67108864);       //   6291456 B bf16 W
  _Float16* zh  = (_Float16*)(ws + 73400320);  //  67108864 B fp16 tanh(Z)
  _Float16* fhg = (_Float16*)(ws + 140509184); //  67108864 B fp16 sigm(F)
  float* ckA    = (float*)(ws + 207618048);    //   2097152 B
  float* ckC    = (float*)(ws + 209715200);    //   2097152 B
  float* carry  = (float*)(ws + 211812352);    //   2097152 B  (total ~204 MiB)

  const int nAll = M_ * K_ / 8 + N_ * K_ / 8;
  cvt_all<<<(nAll + 255) / 256, 256, 0, stream>>>(X, W, Xb, Wb);
  gemm_act<<<dim3(N_ / 256, M_ / 256), 512, 0, stream>>>(Xb, Wb, bias, zh, fhg, Ho);
  scanA<<<dim3(CH_ / 8 / 256, NC_), 256, 0, stream>>>(fhg, zh, ckA, ckC);
  scanComb<<<CH_ / 4 / 64, 64, 0, stream>>>(ckA, ckC, hid, carry);
  scanB<<<dim3(CH_ / 8 / 256, NC_), 256, 0, stream>>>(fhg, zh, Cf, Ho, Clast, carry);
}